// Round 13
// baseline (474.887 us; speedup 1.0000x reference)
//
#include <hip/hip_runtime.h>
#include <math.h>

#define B_ 32
#define T_ 256
#define H_ 128
#define KL_ 500
#define KS_ 10

typedef _Float16 h8 __attribute__((ext_vector_type(8)));  // 16B = 8 fp16
typedef _Float16 h2 __attribute__((ext_vector_type(2)));

// ---------------- K1: convs (+ fused hb) ----------------
__global__ void k_front(const float* __restrict__ in1, const float* __restrict__ in2,
                        const float* __restrict__ wl, const float* __restrict__ bl,
                        const float* __restrict__ ws, const float* __restrict__ bs,
                        const float* __restrict__ h, const float* __restrict__ Whh,
                        const float* __restrict__ bh,
                        float* __restrict__ xf, float* __restrict__ hb,
                        float* __restrict__ dout) {
    int b = blockIdx.x, oc = blockIdx.y;
    int t = threadIdx.x;  // 256 threads
    if (oc == 6) {
        __shared__ float hrow[128];
        if (t < 128) hrow[t] = h[b * 128 + t];
        __syncthreads();
        if (t < 128) {
            float acc = bh[t];
            #pragma unroll 4
            for (int k = 0; k < 128; ++k) acc += hrow[k] * Whh[t * 128 + k];
            hb[b * 128 + t] = acc;
            dout[32 + b * 128 + t] = hrow[t];
        }
        return;
    }
    __shared__ float s_in[755 * 3];
    __shared__ float s_w[3 * KL_];
    if (oc < 3) {
        int o = oc;
        for (int i = t; i < 755 * 3; i += 256) s_in[i] = in1[b * 755 * 3 + i];
        for (int i = t; i < 3 * KL_; i += 256) s_w[i] = wl[o * 3 * KL_ + i];
        __syncthreads();
        float acc = bl[o];
        for (int i = 0; i < 3; ++i) {
            const float* wrow = &s_w[i * KL_];
            #pragma unroll 4
            for (int k = 0; k < KL_; ++k)
                acc += s_in[(t + k) * 3 + i] * wrow[k];
        }
        xf[(b * T_ + t) * 6 + o] = acc;
    } else {
        int o = oc - 3;
        for (int i = t; i < 265 * 3; i += 256) s_in[i] = in2[b * 265 * 3 + i];
        for (int i = t; i < 3 * KS_; i += 256) s_w[i] = ws[o * 3 * KS_ + i];
        __syncthreads();
        float acc = bs[o];
        for (int i = 0; i < 3; ++i) {
            #pragma unroll
            for (int k = 0; k < KS_; ++k)
                acc += s_in[(t + k) * 3 + i] * s_w[i * KS_ + k];
        }
        xf[(b * T_ + t) * 6 + 3 + o] = acc;
    }
}

// ---------------- K2: features -> lane-permuted fp16 tiles ----------------
__global__ void k_feat(const float* __restrict__ xf, const float* __restrict__ in3,
                       const float* __restrict__ hb, const float* __restrict__ Wih,
                       const float* __restrict__ tk, const float* __restrict__ tv,
                       const float* __restrict__ tq,
                       _Float16* __restrict__ rwP, _Float16* __restrict__ clP,
                       float* __restrict__ lblT, float* __restrict__ outq) {
    int t = blockIdx.x;
    int tid = threadIdx.x;
    __shared__ float out_s[B_ * H_];
    __shared__ __align__(16) float tkc[16 * H_];
    __shared__ __align__(16) float tvc[16 * H_];
    __shared__ __align__(16) float tqc[16 * H_];

    for (int o = 0; o < 16; ++o) {
        int idx = o * 256 + tid;
        int b = idx >> 7, hh = idx & 127;
        const float* w = &Wih[hh * 9];
        const float* x6 = &xf[(b * T_ + t) * 6];
        const float* x3 = &in3[(b * T_ + t) * 3];
        float acc = hb[idx];
        acc += x6[0] * w[0] + x6[1] * w[1] + x6[2] * w[2]
             + x6[3] * w[3] + x6[4] * w[4] + x6[5] * w[5]
             + x3[0] * w[6] + x3[1] * w[7] + x3[2] * w[8];
        out_s[idx] = acc;
    }
    __syncthreads();

    float a_tr[16], a_lb[16], a_tq[16];
    #pragma unroll
    for (int o = 0; o < 16; ++o) { a_tr[o] = 0.f; a_lb[o] = 0.f; a_tq[o] = 0.f; }
    const bool last = (t == T_ - 1);

    for (int kc = 0; kc < 8; ++kc) {
        __syncthreads();
        {
            const float4* s1 = (const float4*)(tk + kc * 2048);
            const float4* s2 = (const float4*)(tv + kc * 2048);
            float4* d1 = (float4*)tkc;
            float4* d2 = (float4*)tvc;
            d1[tid * 2]     = s1[tid * 2];
            d1[tid * 2 + 1] = s1[tid * 2 + 1];
            d2[tid * 2]     = s2[tid * 2];
            d2[tid * 2 + 1] = s2[tid * 2 + 1];
            if (last) {
                const float4* s3 = (const float4*)(tq + kc * 2048);
                float4* d3 = (float4*)tqc;
                d3[tid * 2]     = s3[tid * 2];
                d3[tid * 2 + 1] = s3[tid * 2 + 1];
            }
        }
        __syncthreads();
        for (int o = 0; o < 16; ++o) {
            int idx = o * 256 + tid;
            int b = idx >> 7, hh = idx & 127;
            const float* os = &out_s[b * 128 + kc * 16];
            #pragma unroll
            for (int k2 = 0; k2 < 16; ++k2) {
                float ov = os[k2];
                a_tr[o] += ov * tkc[k2 * 128 + hh];
                a_lb[o] += ov * tvc[k2 * 128 + hh];
                if (last) a_tq[o] += ov * tqc[k2 * 128 + hh];
            }
        }
    }
    for (int o = 0; o < 16; ++o) {
        int idx = o * 256 + tid;
        int b = idx >> 7, hh = idx & 127;  // value = trv[t][b][hh]
        _Float16 v16 = (_Float16)a_tr[o];
        int p = hh & 63;
        rwP[t * 4096 + ((p >> 3) << 9) + ((2 * b + (hh >> 6)) << 3) + (p & 7)] = v16;
        int q = ((hh & 1) << 5) + b;
        clP[t * 4096 + ((q >> 3) << 9) + ((hh >> 1) << 3) + (q & 7)] = v16;
        lblT[t * 4096 + hh * 32 + b] = a_lb[o];
        if (last) outq[idx] = a_tq[o];
    }
}

// ---------------- step building blocks ----------------
#define DPP_ADD(S, CTRL)                                                           \
  do { int _d = __builtin_amdgcn_update_dpp(0, __float_as_int(S), (CTRL), 0xF,     \
                                            0xF, true);                            \
       (S) += __int_as_float(_d); } while (0)

#if __has_builtin(__builtin_amdgcn_fdot2)
#define FDOT2(ci, gi, acc)                                                         \
  __builtin_amdgcn_fdot2(__builtin_bit_cast(h2, (ci)),                             \
                         __builtin_bit_cast(h2, (gi)), (acc), false)
#else
static __device__ __forceinline__ float fdot2_sw(int a, int b, float c) {
    h2 ha = __builtin_bit_cast(h2, a), hb2 = __builtin_bit_cast(h2, b);
    return fmaf((float)ha.y, (float)hb2.y, fmaf((float)ha.x, (float)hb2.x, c));
}
#define FDOT2(ci, gi, acc) fdot2_sw((ci), (gi), (acc))
#endif

// ---------------- K3: Adam scan — 8 h per block (8 waves), 2 waves/SIMD ----------------
// Each wave runs an independent 1-h scan (no __syncthreads); waves co-resident
// on a SIMD interleave each other's dependency stalls. All waves in a block read
// the SAME tile addresses each step -> L1-served after the first wave.
__global__
__attribute__((amdgpu_flat_work_group_size(512, 512), amdgpu_waves_per_eu(2)))
void k_scan(
    const _Float16* __restrict__ rwP, const _Float16* __restrict__ clP,
    const float* __restrict__ lblT,
    const float* __restrict__ Wm0, const float* __restrict__ bm0,
    const float* __restrict__ outq, float* __restrict__ hi_ws) {
    const int wid = threadIdx.x >> 6;            // wave 0..7
    const int h = blockIdx.x * 8 + wid;
    const int lane = threadIdx.x & 63;
    const int row = lane >> 1;
    const int hf = lane & 1;
    const int hf32i = hf * 32;           // int-pair base into w16 row
    const int lblidx = h * 32 + row;

    __shared__ __align__(16) int w16[8][64];     // per-wave fp16 w copy (pairs)
    __shared__ __align__(16) float ew[8][128];   // per-wave fp32 epilogue exchange

    // Adam state: lane owns Wm[h][2*lane], Wm[h][2*lane+1]
    float2 wv = *(const float2*)&Wm0[h * 128 + 2 * lane];
    float w0 = wv.x, w1 = wv.y;
    float mW0 = 0.f, vW0 = 0.f, mW1 = 0.f, vW1 = 0.f;
    float bm = bm0[h];
    float mb = 0.f, vb = 0.f, pb1 = 1.f, pb2 = 1.f;

    w16[wid][lane] = __builtin_bit_cast(int, __builtin_amdgcn_cvt_pkrtz(w0, w1));

    h8 rw[8], cl[8];
    float lbl;
    {
        const h8* rs = (const h8*)(rwP);
        const h8* cs = (const h8*)(clP);
        #pragma unroll
        for (int j = 0; j < 8; ++j) rw[j] = rs[j * 64 + lane];
        #pragma unroll
        for (int j = 0; j < 8; ++j) cl[j] = cs[j * 64 + lane];
        lbl = lblT[lblidx];
    }

    const float cg = 2.0f / 4096.0f;
    const float lr = 0.01f, BB1 = 0.9f, BB2 = 0.999f;
    const float OB1 = 0.1f, OB2 = 0.001f;
    const float SEPS = 1e-16f;

    for (int t = 0; t < T_; ++t) {
        pb1 *= BB1; pb2 *= BB2;
        const float na = (-lr) * __builtin_amdgcn_sqrtf(1.0f - pb2) *
                         __builtin_amdgcn_rcpf(1.0f - pb1);
        const int tpre = (t + 1 < T_) ? (t + 1) : (T_ - 1);

        // ---- phase A: pred via fdot2 against fp16 w in LDS ----
        float g;
        {
            float f0 = 0.f, f1 = 0.f, f2 = 0.f, f3 = 0.f;
            #pragma unroll
            for (int j = 0; j < 8; ++j) {
                int4 xj = __builtin_bit_cast(int4, rw[j]);
                int4 wj = *(const int4*)&w16[wid][hf32i + 4 * j];
                f0 = FDOT2(xj.x, wj.x, f0); f1 = FDOT2(xj.y, wj.y, f1);
                f2 = FDOT2(xj.z, wj.z, f2); f3 = FDOT2(xj.w, wj.w, f3);
            }
            float pp = (f0 + f2) + (f1 + f3);
            int po = __builtin_amdgcn_update_dpp(0, __float_as_int(pp), 0xB1, 0xF, 0xF, true);
            g = (pp + __int_as_float(po)) + bm - lbl;   // unscaled grad
        }

        // prefetch rows + lbl for t+1 (rw just consumed)
        {
            const h8* rs = (const h8*)(rwP + (size_t)tpre * 4096);
            #pragma unroll
            for (int j = 0; j < 8; ++j) rw[j] = rs[j * 64 + lane];
            lbl = lblT[(size_t)tpre * 4096 + lblidx];
        }

        // pack (g[2i], g[2i+1]) on lanes 4i
        int pkg;
        {
            int gnb = __builtin_amdgcn_update_dpp(0, __float_as_int(g), 0x4E, 0xF, 0xF, true);
            pkg = __builtin_bit_cast(int,
                __builtin_amdgcn_cvt_pkrtz(g, __int_as_float(gnb)));
        }
        // bias grad: exact fp32 butterfly over the 32 distinct g's
        float gsum = g;
        DPP_ADD(gsum, 0x4E); DPP_ADD(gsum, 0x124); DPP_ADD(gsum, 0x128);
        gsum += __shfl_xor(gsum, 16); gsum += __shfl_xor(gsum, 32);

        // 16 packed readlanes
        int gp[16];
        #pragma unroll
        for (int i = 0; i < 16; ++i)
            gp[i] = __builtin_amdgcn_readlane(pkg, 4 * i);

        // ---- phase B: 32 dot2 for this lane's two columns ----
        float gk0, gk1;
        {
            float f0 = 0.f, f1 = 0.f, f2 = 0.f, f3 = 0.f;
            float f4 = 0.f, f5 = 0.f, f6 = 0.f, f7 = 0.f;
            #pragma unroll
            for (int j = 0; j < 4; ++j) {
                int4 cj = __builtin_bit_cast(int4, cl[j]);
                f0 = FDOT2(cj.x, gp[4 * j + 0], f0); f1 = FDOT2(cj.y, gp[4 * j + 1], f1);
                f2 = FDOT2(cj.z, gp[4 * j + 2], f2); f3 = FDOT2(cj.w, gp[4 * j + 3], f3);
            }
            #pragma unroll
            for (int j = 0; j < 4; ++j) {
                int4 cj = __builtin_bit_cast(int4, cl[j + 4]);
                f4 = FDOT2(cj.x, gp[4 * j + 0], f4); f5 = FDOT2(cj.y, gp[4 * j + 1], f5);
                f6 = FDOT2(cj.z, gp[4 * j + 2], f6); f7 = FDOT2(cj.w, gp[4 * j + 3], f7);
            }
            gk0 = cg * ((f0 + f2) + (f1 + f3));
            gk1 = cg * ((f4 + f6) + (f5 + f7));
        }

        // prefetch cols for t+1 (cl just consumed)
        {
            const h8* cs = (const h8*)(clP + (size_t)tpre * 4096);
            #pragma unroll
            for (int j = 0; j < 8; ++j) cl[j] = cs[j * 64 + lane];
        }

        // ---- Adam W ----
        mW0 = fmaf(BB1, mW0, OB1 * gk0);
        vW0 = fmaf(BB2, vW0, OB2 * gk0 * gk0);
        w0 = fmaf(mW0 * __builtin_amdgcn_rsqf(vW0 + SEPS), na, w0);
        mW1 = fmaf(BB1, mW1, OB1 * gk1);
        vW1 = fmaf(BB2, vW1, OB2 * gk1 * gk1);
        w1 = fmaf(mW1 * __builtin_amdgcn_rsqf(vW1 + SEPS), na, w1);

        w16[wid][lane] = __builtin_bit_cast(int, __builtin_amdgcn_cvt_pkrtz(w0, w1));

        // bias Adam (redundant on all lanes; off the w critical chain)
        {
            float gb = cg * gsum;
            mb = fmaf(BB1, mb, OB1 * gb);
            vb = fmaf(BB2, vb, OB2 * gb * gb);
            bm = fmaf(mb * __builtin_amdgcn_rsqf(vb + SEPS), na, bm);
        }
    }

    // ---- epilogue: hi[:,h] = outq @ Wm_final[h,:] + bm_final (fp32 exact) ----
    *(float2*)&ew[wid][2 * lane] = make_float2(w0, w1);
    {
        const int rowbase = row * 128 + hf * 64;
        float a0 = 0.f, a1 = 0.f, a2 = 0.f, a3 = 0.f;
        #pragma unroll
        for (int j = 0; j < 16; ++j) {
            float4 xv = ((const float4*)(outq + rowbase))[j];
            float4 wv4 = *(const float4*)&ew[wid][hf * 64 + 4 * j];
            a0 = fmaf(xv.x, wv4.x, a0); a1 = fmaf(xv.y, wv4.y, a1);
            a2 = fmaf(xv.z, wv4.z, a2); a3 = fmaf(xv.w, wv4.w, a3);
        }
        float pp = (a0 + a2) + (a1 + a3);
        int po = __builtin_amdgcn_update_dpp(0, __float_as_int(pp), 0xB1, 0xF, 0xF, true);
        float pred = pp + __int_as_float(po);
        if (hf == 0) hi_ws[row * 128 + h] = pred + bm;
    }
}

// ---------------- K4: y = hi@W_ho.T + b_o ; out = y@out_W.T + out_b ----------------
__global__ void k_out(const float* __restrict__ hi, const float* __restrict__ Who,
                      const float* __restrict__ bo, const float* __restrict__ outW,
                      const float* __restrict__ outb, float* __restrict__ dout) {
    int b = blockIdx.x, hh = threadIdx.x;
    __shared__ float hrow[128];
    __shared__ float part[2];
    hrow[hh] = hi[b * 128 + hh];
    __syncthreads();
    float acc = bo[hh];
    #pragma unroll 4
    for (int k = 0; k < 128; ++k) acc += hrow[k] * Who[hh * 128 + k];
    float v = acc * outW[hh];
    v += __shfl_down(v, 32, 64);
    v += __shfl_down(v, 16, 64);
    v += __shfl_down(v, 8, 64);
    v += __shfl_down(v, 4, 64);
    v += __shfl_down(v, 2, 64);
    v += __shfl_down(v, 1, 64);
    if ((hh & 63) == 0) part[hh >> 6] = v;
    __syncthreads();
    if (hh == 0) dout[b] = part[0] + part[1] + outb[0];
}

extern "C" void kernel_launch(void* const* d_in, const int* in_sizes, int n_in,
                              void* d_out, int out_size, void* d_ws, size_t ws_size,
                              hipStream_t stream) {
    (void)in_sizes; (void)n_in; (void)out_size; (void)ws_size;
    const float* in1   = (const float*)d_in[0];
    const float* in2   = (const float*)d_in[1];
    const float* in3   = (const float*)d_in[2];
    const float* h     = (const float*)d_in[3];
    const float* Wih   = (const float*)d_in[4];
    const float* Whh   = (const float*)d_in[5];
    const float* bh    = (const float*)d_in[6];
    const float* Who   = (const float*)d_in[7];
    const float* bo    = (const float*)d_in[8];
    const float* wl    = (const float*)d_in[9];
    const float* bl    = (const float*)d_in[10];
    const float* wsc   = (const float*)d_in[11];
    const float* bsc   = (const float*)d_in[12];
    const float* tk    = (const float*)d_in[13];
    const float* tv    = (const float*)d_in[14];
    const float* tq    = (const float*)d_in[15];
    const float* Wm0   = (const float*)d_in[16];
    const float* bm0   = (const float*)d_in[17];
    const float* outW  = (const float*)d_in[18];
    const float* outb  = (const float*)d_in[19];
    float* out = (float*)d_out;

    float* wsf = (float*)d_ws;
    float*    xf    = wsf;                               // 49152 f
    float*    hb    = wsf + 49152;                       // 4096 f
    _Float16* rwH   = (_Float16*)(wsf + 53248);          // 1048576 halfs
    _Float16* clH   = (_Float16*)(wsf + 53248 + 524288); // 1048576 halfs
    float*    lblT  = wsf + 53248 + 1048576;             // 1048576 f
    float*    outq  = wsf + 53248 + 2097152;             // 4096 f
    float*    hi_ws = wsf + 53248 + 2101248;             // 4096 f

    k_front<<<dim3(32, 7), 256, 0, stream>>>(in1, in2, wl, bl, wsc, bsc,
                                             h, Whh, bh, xf, hb, out);
    k_feat<<<256, 256, 0, stream>>>(xf, in3, hb, Wih, tk, tv, tq,
                                    rwH, clH, lblT, outq);
    k_scan<<<16, 512, 0, stream>>>(rwH, clH, lblT, Wm0, bm0, outq, hi_ws);
    k_out<<<32, 128, 0, stream>>>(hi_ws, Who, bo, outW, outb, out);
}

// Round 14
// 262.924 us; speedup vs baseline: 1.8062x; 1.8062x over previous
//
#include <hip/hip_runtime.h>
#include <math.h>

#define B_ 32
#define T_ 256
#define H_ 128
#define KL_ 500
#define KS_ 10

typedef _Float16 h8 __attribute__((ext_vector_type(8)));  // 16B = 8 fp16
typedef _Float16 h2 __attribute__((ext_vector_type(2)));

// ---------------- K1: convs (+ fused hb) ----------------
__global__ void k_front(const float* __restrict__ in1, const float* __restrict__ in2,
                        const float* __restrict__ wl, const float* __restrict__ bl,
                        const float* __restrict__ ws, const float* __restrict__ bs,
                        const float* __restrict__ h, const float* __restrict__ Whh,
                        const float* __restrict__ bh,
                        float* __restrict__ xf, float* __restrict__ hb,
                        float* __restrict__ dout) {
    int b = blockIdx.x, oc = blockIdx.y;
    int t = threadIdx.x;  // 256 threads
    if (oc == 6) {
        __shared__ float hrow[128];
        if (t < 128) hrow[t] = h[b * 128 + t];
        __syncthreads();
        if (t < 128) {
            float acc = bh[t];
            #pragma unroll 4
            for (int k = 0; k < 128; ++k) acc += hrow[k] * Whh[t * 128 + k];
            hb[b * 128 + t] = acc;
            dout[32 + b * 128 + t] = hrow[t];
        }
        return;
    }
    __shared__ float s_in[755 * 3];
    __shared__ float s_w[3 * KL_];
    if (oc < 3) {
        int o = oc;
        for (int i = t; i < 755 * 3; i += 256) s_in[i] = in1[b * 755 * 3 + i];
        for (int i = t; i < 3 * KL_; i += 256) s_w[i] = wl[o * 3 * KL_ + i];
        __syncthreads();
        float acc = bl[o];
        for (int i = 0; i < 3; ++i) {
            const float* wrow = &s_w[i * KL_];
            #pragma unroll 4
            for (int k = 0; k < KL_; ++k)
                acc += s_in[(t + k) * 3 + i] * wrow[k];
        }
        xf[(b * T_ + t) * 6 + o] = acc;
    } else {
        int o = oc - 3;
        for (int i = t; i < 265 * 3; i += 256) s_in[i] = in2[b * 265 * 3 + i];
        for (int i = t; i < 3 * KS_; i += 256) s_w[i] = ws[o * 3 * KS_ + i];
        __syncthreads();
        float acc = bs[o];
        for (int i = 0; i < 3; ++i) {
            #pragma unroll
            for (int k = 0; k < KS_; ++k)
                acc += s_in[(t + k) * 3 + i] * s_w[i * KS_ + k];
        }
        xf[(b * T_ + t) * 6 + 3 + o] = acc;
    }
}

// ---------------- K2: features -> lane-permuted fp16 tiles ----------------
// Inner loop restructured: tkc/tvc column values hoisted to registers (o-invariant),
// out_s rows read as float4 broadcasts. 8x fewer LDS issue slots than v12.
__global__ void k_feat(const float* __restrict__ xf, const float* __restrict__ in3,
                       const float* __restrict__ hb, const float* __restrict__ Wih,
                       const float* __restrict__ tk, const float* __restrict__ tv,
                       const float* __restrict__ tq,
                       _Float16* __restrict__ rwP, _Float16* __restrict__ clP,
                       float* __restrict__ lblT, float* __restrict__ outq) {
    int t = blockIdx.x;
    int tid = threadIdx.x;
    const int hh = tid & 127;
    __shared__ __align__(16) float out_s[B_ * H_];
    __shared__ __align__(16) float tkc[16 * H_];
    __shared__ __align__(16) float tvc[16 * H_];
    __shared__ __align__(16) float tqc[16 * H_];

    for (int o = 0; o < 16; ++o) {
        int idx = o * 256 + tid;
        int b = idx >> 7, hx = idx & 127;
        const float* w = &Wih[hx * 9];
        const float* x6 = &xf[(b * T_ + t) * 6];
        const float* x3 = &in3[(b * T_ + t) * 3];
        float acc = hb[idx];
        acc += x6[0] * w[0] + x6[1] * w[1] + x6[2] * w[2]
             + x6[3] * w[3] + x6[4] * w[4] + x6[5] * w[5]
             + x3[0] * w[6] + x3[1] * w[7] + x3[2] * w[8];
        out_s[idx] = acc;
    }
    __syncthreads();

    float a_tr[16], a_lb[16], a_tq[16];
    #pragma unroll
    for (int o = 0; o < 16; ++o) { a_tr[o] = 0.f; a_lb[o] = 0.f; a_tq[o] = 0.f; }
    const bool last = (t == T_ - 1);

    for (int kc = 0; kc < 8; ++kc) {
        __syncthreads();
        {
            const float4* s1 = (const float4*)(tk + kc * 2048);
            const float4* s2 = (const float4*)(tv + kc * 2048);
            float4* d1 = (float4*)tkc;
            float4* d2 = (float4*)tvc;
            d1[tid * 2]     = s1[tid * 2];
            d1[tid * 2 + 1] = s1[tid * 2 + 1];
            d2[tid * 2]     = s2[tid * 2];
            d2[tid * 2 + 1] = s2[tid * 2 + 1];
            if (last) {
                const float4* s3 = (const float4*)(tq + kc * 2048);
                float4* d3 = (float4*)tqc;
                d3[tid * 2]     = s3[tid * 2];
                d3[tid * 2 + 1] = s3[tid * 2 + 1];
            }
        }
        __syncthreads();

        // hoist the k2-columns for this thread's hh (o-invariant)
        float tkr[16], tvr[16], tqr[16];
        #pragma unroll
        for (int k2 = 0; k2 < 16; ++k2) {
            tkr[k2] = tkc[k2 * 128 + hh];
            tvr[k2] = tvc[k2 * 128 + hh];
        }
        if (last) {
            #pragma unroll
            for (int k2 = 0; k2 < 16; ++k2) tqr[k2] = tqc[k2 * 128 + hh];
        }

        #pragma unroll
        for (int o = 0; o < 16; ++o) {
            int b = o * 2 + (tid >> 7);
            const float4* os4 = (const float4*)&out_s[b * 128 + kc * 16];
            float4 q0 = os4[0], q1 = os4[1], q2 = os4[2], q3 = os4[3];
            float osv[16] = {q0.x, q0.y, q0.z, q0.w, q1.x, q1.y, q1.z, q1.w,
                             q2.x, q2.y, q2.z, q2.w, q3.x, q3.y, q3.z, q3.w};
            #pragma unroll
            for (int k2 = 0; k2 < 16; ++k2) {
                a_tr[o] = fmaf(osv[k2], tkr[k2], a_tr[o]);
                a_lb[o] = fmaf(osv[k2], tvr[k2], a_lb[o]);
                if (last) a_tq[o] = fmaf(osv[k2], tqr[k2], a_tq[o]);
            }
        }
    }
    for (int o = 0; o < 16; ++o) {
        int idx = o * 256 + tid;
        int b = idx >> 7;  // value = trv[t][b][hh]
        _Float16 v16 = (_Float16)a_tr[o];
        int p = hh & 63;
        rwP[t * 4096 + ((p >> 3) << 9) + ((2 * b + (hh >> 6)) << 3) + (p & 7)] = v16;
        int q = ((hh & 1) << 5) + b;
        clP[t * 4096 + ((q >> 3) << 9) + ((hh >> 1) << 3) + (q & 7)] = v16;
        lblT[t * 4096 + hh * 32 + b] = a_lb[o];
        if (last) outq[idx] = a_tq[o];
    }
}

// ---------------- step building blocks ----------------
#define DPP_ADD(S, CTRL)                                                           \
  do { int _d = __builtin_amdgcn_update_dpp(0, __float_as_int(S), (CTRL), 0xF,     \
                                            0xF, true);                            \
       (S) += __int_as_float(_d); } while (0)

#if __has_builtin(__builtin_amdgcn_fdot2)
#define FDOT2(ci, gi, acc)                                                         \
  __builtin_amdgcn_fdot2(__builtin_bit_cast(h2, (ci)),                             \
                         __builtin_bit_cast(h2, (gi)), (acc), false)
#else
static __device__ __forceinline__ float fdot2_sw(int a, int b, float c) {
    h2 ha = __builtin_bit_cast(h2, a), hb2 = __builtin_bit_cast(h2, b);
    return fmaf((float)ha.y, (float)hb2.y, fmaf((float)ha.x, (float)hb2.x, c));
}
#define FDOT2(ci, gi, acc) fdot2_sw((ci), (gi), (acc))
#endif

// ---------------- K3: Adam scan — 1 h per wave, lean fdot2 step (r12) ----------------
__global__
__attribute__((amdgpu_flat_work_group_size(64, 64), amdgpu_waves_per_eu(1, 1)))
void k_scan(
    const _Float16* __restrict__ rwP, const _Float16* __restrict__ clP,
    const float* __restrict__ lblT,
    const float* __restrict__ Wm0, const float* __restrict__ bm0,
    const float* __restrict__ outq, float* __restrict__ hi_ws) {
    const int h = blockIdx.x;
    const int lane = threadIdx.x;
    const int row = lane >> 1;
    const int hf = lane & 1;
    const int hf32i = hf * 32;           // int-pair base into w16
    const int lblidx = h * 32 + row;

    __shared__ __align__(16) int w16[64];      // fp16 w copy (pairs)
    __shared__ __align__(16) float ew[128];    // fp32 epilogue exchange

    // Adam state: lane owns Wm[h][2*lane], Wm[h][2*lane+1]
    float2 wv = *(const float2*)&Wm0[h * 128 + 2 * lane];
    float w0 = wv.x, w1 = wv.y;
    float mW0 = 0.f, vW0 = 0.f, mW1 = 0.f, vW1 = 0.f;
    float bm = bm0[h];
    float mb = 0.f, vb = 0.f, pb1 = 1.f, pb2 = 1.f;

    w16[lane] = __builtin_bit_cast(int, __builtin_amdgcn_cvt_pkrtz(w0, w1));

    h8 rw[8], cl[8];
    float lbl;
    {
        const h8* rs = (const h8*)(rwP);
        const h8* cs = (const h8*)(clP);
        #pragma unroll
        for (int j = 0; j < 8; ++j) rw[j] = rs[j * 64 + lane];
        #pragma unroll
        for (int j = 0; j < 8; ++j) cl[j] = cs[j * 64 + lane];
        lbl = lblT[lblidx];
    }

    const float cg = 2.0f / 4096.0f;
    const float lr = 0.01f, BB1 = 0.9f, BB2 = 0.999f;
    const float OB1 = 0.1f, OB2 = 0.001f;
    const float SEPS = 1e-16f;

    for (int t = 0; t < T_; ++t) {
        pb1 *= BB1; pb2 *= BB2;
        const float na = (-lr) * __builtin_amdgcn_sqrtf(1.0f - pb2) *
                         __builtin_amdgcn_rcpf(1.0f - pb1);
        const int tpre = (t + 1 < T_) ? (t + 1) : (T_ - 1);

        // ---- phase A: pred via fdot2 against fp16 w in LDS ----
        float g;
        {
            float f0 = 0.f, f1 = 0.f, f2 = 0.f, f3 = 0.f;
            #pragma unroll
            for (int j = 0; j < 8; ++j) {
                int4 xj = __builtin_bit_cast(int4, rw[j]);
                int4 wj = *(const int4*)&w16[hf32i + 4 * j];
                f0 = FDOT2(xj.x, wj.x, f0); f1 = FDOT2(xj.y, wj.y, f1);
                f2 = FDOT2(xj.z, wj.z, f2); f3 = FDOT2(xj.w, wj.w, f3);
            }
            float pp = (f0 + f2) + (f1 + f3);
            int po = __builtin_amdgcn_update_dpp(0, __float_as_int(pp), 0xB1, 0xF, 0xF, true);
            g = (pp + __int_as_float(po)) + bm - lbl;   // unscaled grad
        }

        // prefetch rows + lbl for t+1 (rw just consumed)
        {
            const h8* rs = (const h8*)(rwP + (size_t)tpre * 4096);
            #pragma unroll
            for (int j = 0; j < 8; ++j) rw[j] = rs[j * 64 + lane];
            lbl = lblT[(size_t)tpre * 4096 + lblidx];
        }

        // pack (g[2i], g[2i+1]) on lanes 4i
        int pkg;
        {
            int gnb = __builtin_amdgcn_update_dpp(0, __float_as_int(g), 0x4E, 0xF, 0xF, true);
            pkg = __builtin_bit_cast(int,
                __builtin_amdgcn_cvt_pkrtz(g, __int_as_float(gnb)));
        }
        // bias grad: exact fp32 butterfly over the 32 distinct g's
        float gsum = g;
        DPP_ADD(gsum, 0x4E); DPP_ADD(gsum, 0x124); DPP_ADD(gsum, 0x128);
        gsum += __shfl_xor(gsum, 16); gsum += __shfl_xor(gsum, 32);

        // 16 packed readlanes
        int gp[16];
        #pragma unroll
        for (int i = 0; i < 16; ++i)
            gp[i] = __builtin_amdgcn_readlane(pkg, 4 * i);

        // ---- phase B: 32 dot2 for this lane's two columns ----
        float gk0, gk1;
        {
            float f0 = 0.f, f1 = 0.f, f2 = 0.f, f3 = 0.f;
            float f4 = 0.f, f5 = 0.f, f6 = 0.f, f7 = 0.f;
            #pragma unroll
            for (int j = 0; j < 4; ++j) {
                int4 cj = __builtin_bit_cast(int4, cl[j]);
                f0 = FDOT2(cj.x, gp[4 * j + 0], f0); f1 = FDOT2(cj.y, gp[4 * j + 1], f1);
                f2 = FDOT2(cj.z, gp[4 * j + 2], f2); f3 = FDOT2(cj.w, gp[4 * j + 3], f3);
            }
            #pragma unroll
            for (int j = 0; j < 4; ++j) {
                int4 cj = __builtin_bit_cast(int4, cl[j + 4]);
                f4 = FDOT2(cj.x, gp[4 * j + 0], f4); f5 = FDOT2(cj.y, gp[4 * j + 1], f5);
                f6 = FDOT2(cj.z, gp[4 * j + 2], f6); f7 = FDOT2(cj.w, gp[4 * j + 3], f7);
            }
            gk0 = cg * ((f0 + f2) + (f1 + f3));
            gk1 = cg * ((f4 + f6) + (f5 + f7));
        }

        // prefetch cols for t+1 (cl just consumed)
        {
            const h8* cs = (const h8*)(clP + (size_t)tpre * 4096);
            #pragma unroll
            for (int j = 0; j < 8; ++j) cl[j] = cs[j * 64 + lane];
        }

        // ---- Adam W ----
        mW0 = fmaf(BB1, mW0, OB1 * gk0);
        vW0 = fmaf(BB2, vW0, OB2 * gk0 * gk0);
        w0 = fmaf(mW0 * __builtin_amdgcn_rsqf(vW0 + SEPS), na, w0);
        mW1 = fmaf(BB1, mW1, OB1 * gk1);
        vW1 = fmaf(BB2, vW1, OB2 * gk1 * gk1);
        w1 = fmaf(mW1 * __builtin_amdgcn_rsqf(vW1 + SEPS), na, w1);

        w16[lane] = __builtin_bit_cast(int, __builtin_amdgcn_cvt_pkrtz(w0, w1));

        // bias Adam (redundant on all lanes; off the w critical chain)
        {
            float gb = cg * gsum;
            mb = fmaf(BB1, mb, OB1 * gb);
            vb = fmaf(BB2, vb, OB2 * gb * gb);
            bm = fmaf(mb * __builtin_amdgcn_rsqf(vb + SEPS), na, bm);
        }
    }

    // ---- epilogue: hi[:,h] = outq @ Wm_final[h,:] + bm_final (fp32 exact) ----
    *(float2*)&ew[2 * lane] = make_float2(w0, w1);
    {
        const int rowbase = row * 128 + hf * 64;
        float a0 = 0.f, a1 = 0.f, a2 = 0.f, a3 = 0.f;
        #pragma unroll
        for (int j = 0; j < 16; ++j) {
            float4 xv = ((const float4*)(outq + rowbase))[j];
            float4 wv4 = *(const float4*)&ew[hf * 64 + 4 * j];
            a0 = fmaf(xv.x, wv4.x, a0); a1 = fmaf(xv.y, wv4.y, a1);
            a2 = fmaf(xv.z, wv4.z, a2); a3 = fmaf(xv.w, wv4.w, a3);
        }
        float pp = (a0 + a2) + (a1 + a3);
        int po = __builtin_amdgcn_update_dpp(0, __float_as_int(pp), 0xB1, 0xF, 0xF, true);
        float pred = pp + __int_as_float(po);
        if (hf == 0) hi_ws[row * 128 + h] = pred + bm;
    }
}

// ---------------- K4: y = hi@W_ho.T + b_o ; out = y@out_W.T + out_b ----------------
__global__ void k_out(const float* __restrict__ hi, const float* __restrict__ Who,
                      const float* __restrict__ bo, const float* __restrict__ outW,
                      const float* __restrict__ outb, float* __restrict__ dout) {
    int b = blockIdx.x, hh = threadIdx.x;
    __shared__ float hrow[128];
    __shared__ float part[2];
    hrow[hh] = hi[b * 128 + hh];
    __syncthreads();
    float acc = bo[hh];
    #pragma unroll 4
    for (int k = 0; k < 128; ++k) acc += hrow[k] * Who[hh * 128 + k];
    float v = acc * outW[hh];
    v += __shfl_down(v, 32, 64);
    v += __shfl_down(v, 16, 64);
    v += __shfl_down(v, 8, 64);
    v += __shfl_down(v, 4, 64);
    v += __shfl_down(v, 2, 64);
    v += __shfl_down(v, 1, 64);
    if ((hh & 63) == 0) part[hh >> 6] = v;
    __syncthreads();
    if (hh == 0) dout[b] = part[0] + part[1] + outb[0];
}

extern "C" void kernel_launch(void* const* d_in, const int* in_sizes, int n_in,
                              void* d_out, int out_size, void* d_ws, size_t ws_size,
                              hipStream_t stream) {
    (void)in_sizes; (void)n_in; (void)out_size; (void)ws_size;
    const float* in1   = (const float*)d_in[0];
    const float* in2   = (const float*)d_in[1];
    const float* in3   = (const float*)d_in[2];
    const float* h     = (const float*)d_in[3];
    const float* Wih   = (const float*)d_in[4];
    const float* Whh   = (const float*)d_in[5];
    const float* bh    = (const float*)d_in[6];
    const float* Who   = (const float*)d_in[7];
    const float* bo    = (const float*)d_in[8];
    const float* wl    = (const float*)d_in[9];
    const float* bl    = (const float*)d_in[10];
    const float* wsc   = (const float*)d_in[11];
    const float* bsc   = (const float*)d_in[12];
    const float* tk    = (const float*)d_in[13];
    const float* tv    = (const float*)d_in[14];
    const float* tq    = (const float*)d_in[15];
    const float* Wm0   = (const float*)d_in[16];
    const float* bm0   = (const float*)d_in[17];
    const float* outW  = (const float*)d_in[18];
    const float* outb  = (const float*)d_in[19];
    float* out = (float*)d_out;

    float* wsf = (float*)d_ws;
    float*    xf    = wsf;                               // 49152 f
    float*    hb    = wsf + 49152;                       // 4096 f
    _Float16* rwH   = (_Float16*)(wsf + 53248);          // 1048576 halfs
    _Float16* clH   = (_Float16*)(wsf + 53248 + 524288); // 1048576 halfs
    float*    lblT  = wsf + 53248 + 1048576;             // 1048576 f
    float*    outq  = wsf + 53248 + 2097152;             // 4096 f
    float*    hi_ws = wsf + 53248 + 2101248;             // 4096 f

    k_front<<<dim3(32, 7), 256, 0, stream>>>(in1, in2, wl, bl, wsc, bsc,
                                             h, Whh, bh, xf, hb, out);
    k_feat<<<256, 256, 0, stream>>>(xf, in3, hb, Wih, tk, tv, tq,
                                    rwH, clH, lblT, outq);
    k_scan<<<128, 64, 0, stream>>>(rwH, clH, lblT, Wm0, bm0, outq, hi_ws);
    k_out<<<32, 128, 0, stream>>>(hi_ws, Who, bo, outW, outb, out);
}

// Round 15
// 197.968 us; speedup vs baseline: 2.3988x; 1.3281x over previous
//
#include <hip/hip_runtime.h>
#include <math.h>

#define B_ 32
#define T_ 256
#define H_ 128
#define KL_ 500
#define KS_ 10

typedef _Float16 h8 __attribute__((ext_vector_type(8)));  // 16B = 8 fp16
typedef _Float16 h2 __attribute__((ext_vector_type(2)));

// ---------------- K1: convs (+ fused hb) ----------------
__global__ void k_front(const float* __restrict__ in1, const float* __restrict__ in2,
                        const float* __restrict__ wl, const float* __restrict__ bl,
                        const float* __restrict__ ws, const float* __restrict__ bs,
                        const float* __restrict__ h, const float* __restrict__ Whh,
                        const float* __restrict__ bh,
                        float* __restrict__ xf, float* __restrict__ hb,
                        float* __restrict__ dout) {
    int b = blockIdx.x, oc = blockIdx.y;
    int t = threadIdx.x;  // 256 threads
    if (oc == 6) {
        __shared__ float hrow[128];
        if (t < 128) hrow[t] = h[b * 128 + t];
        __syncthreads();
        if (t < 128) {
            float acc = bh[t];
            #pragma unroll 4
            for (int k = 0; k < 128; ++k) acc += hrow[k] * Whh[t * 128 + k];
            hb[b * 128 + t] = acc;
            dout[32 + b * 128 + t] = hrow[t];
        }
        return;
    }
    __shared__ float s_in[755 * 3];
    __shared__ float s_w[3 * KL_];
    if (oc < 3) {
        int o = oc;
        for (int i = t; i < 755 * 3; i += 256) s_in[i] = in1[b * 755 * 3 + i];
        for (int i = t; i < 3 * KL_; i += 256) s_w[i] = wl[o * 3 * KL_ + i];
        __syncthreads();
        float acc = bl[o];
        for (int i = 0; i < 3; ++i) {
            const float* wrow = &s_w[i * KL_];
            #pragma unroll 4
            for (int k = 0; k < KL_; ++k)
                acc += s_in[(t + k) * 3 + i] * wrow[k];
        }
        xf[(b * T_ + t) * 6 + o] = acc;
    } else {
        int o = oc - 3;
        for (int i = t; i < 265 * 3; i += 256) s_in[i] = in2[b * 265 * 3 + i];
        for (int i = t; i < 3 * KS_; i += 256) s_w[i] = ws[o * 3 * KS_ + i];
        __syncthreads();
        float acc = bs[o];
        for (int i = 0; i < 3; ++i) {
            #pragma unroll
            for (int k = 0; k < KS_; ++k)
                acc += s_in[(t + k) * 3 + i] * s_w[i * KS_ + k];
        }
        xf[(b * T_ + t) * 6 + 3 + o] = acc;
    }
}

// ---------------- K2: features -> lane-permuted fp16 tiles ----------------
// One-time staging: tk/tv (+tq on last t) as fp16 TRANSPOSED [hh][k] (stride 136
// halves = 272B, 16B-aligned), out_s fp32. Single barrier; inner loop is
// fma_mix (fp16 tk x fp32 out) with broadcast out-row reads. 512 threads.
#define TSTR 136

__global__ void k_feat(const float* __restrict__ xf, const float* __restrict__ in3,
                       const float* __restrict__ hb, const float* __restrict__ Wih,
                       const float* __restrict__ tk, const float* __restrict__ tv,
                       const float* __restrict__ tq,
                       _Float16* __restrict__ rwP, _Float16* __restrict__ clP,
                       float* __restrict__ lblT, float* __restrict__ outq) {
    int t = blockIdx.x;
    int tid = threadIdx.x;             // 0..511
    const int hh = tid & 127;
    const int grp = tid >> 7;          // 0..3
    const bool last = (t == T_ - 1);

    __shared__ __align__(16) _Float16 tkT[128 * TSTR];
    __shared__ __align__(16) _Float16 tvT[128 * TSTR];
    __shared__ __align__(16) _Float16 tqT[128 * TSTR];
    __shared__ __align__(16) float out_s[B_ * H_];

    // stage out_s (fp32): idx = j*512 + tid
    for (int j = 0; j < 8; ++j) {
        int idx = j * 512 + tid;
        int b = idx >> 7, hx = idx & 127;
        const float* w = &Wih[hx * 9];
        const float* x6 = &xf[(b * T_ + t) * 6];
        const float* x3 = &in3[(b * T_ + t) * 3];
        float acc = hb[idx];
        acc += x6[0] * w[0] + x6[1] * w[1] + x6[2] * w[2]
             + x6[3] * w[3] + x6[4] * w[4] + x6[5] * w[5]
             + x3[0] * w[6] + x3[1] * w[7] + x3[2] * w[8];
        out_s[idx] = acc;
    }
    // stage tk/tv transposed fp16 (coalesced reads; scattered u16 writes, once)
    for (int i = tid; i < 16384; i += 512) {
        int k = i >> 7, hx = i & 127;
        tkT[hx * TSTR + k] = (_Float16)tk[i];
        tvT[hx * TSTR + k] = (_Float16)tv[i];
    }
    if (last) {
        for (int i = tid; i < 16384; i += 512) {
            int k = i >> 7, hx = i & 127;
            tqT[hx * TSTR + k] = (_Float16)tq[i];
        }
    }
    __syncthreads();

    float a_tr[8], a_lb[8], a_tq[8];
    #pragma unroll
    for (int o = 0; o < 8; ++o) { a_tr[o] = 0.f; a_lb[o] = 0.f; a_tq[o] = 0.f; }

    for (int kc = 0; kc < 8; ++kc) {
        // hoist this thread's 16-k chunks of tkT[hh]/tvT[hh] (2 b128 each)
        const int4* tk4 = (const int4*)&tkT[hh * TSTR + kc * 16];
        const int4* tv4 = (const int4*)&tvT[hh * TSTR + kc * 16];
        h8 ka = __builtin_bit_cast(h8, tk4[0]), kb = __builtin_bit_cast(h8, tk4[1]);
        h8 va = __builtin_bit_cast(h8, tv4[0]), vb = __builtin_bit_cast(h8, tv4[1]);
        h8 qa, qb;
        if (last) {
            const int4* tq4 = (const int4*)&tqT[hh * TSTR + kc * 16];
            qa = __builtin_bit_cast(h8, tq4[0]); qb = __builtin_bit_cast(h8, tq4[1]);
        }
        #pragma unroll
        for (int o = 0; o < 8; ++o) {
            int b = o * 4 + grp;
            const float4* os4 = (const float4*)&out_s[b * 128 + kc * 16];
            float4 q0 = os4[0], q1 = os4[1], q2 = os4[2], q3 = os4[3];
            float osv[16] = {q0.x, q0.y, q0.z, q0.w, q1.x, q1.y, q1.z, q1.w,
                             q2.x, q2.y, q2.z, q2.w, q3.x, q3.y, q3.z, q3.w};
            #pragma unroll
            for (int k2 = 0; k2 < 8; ++k2) {
                a_tr[o] = fmaf(osv[k2], (float)ka[k2], a_tr[o]);
                a_lb[o] = fmaf(osv[k2], (float)va[k2], a_lb[o]);
                if (last) a_tq[o] = fmaf(osv[k2], (float)qa[k2], a_tq[o]);
            }
            #pragma unroll
            for (int k2 = 0; k2 < 8; ++k2) {
                a_tr[o] = fmaf(osv[8 + k2], (float)kb[k2], a_tr[o]);
                a_lb[o] = fmaf(osv[8 + k2], (float)vb[k2], a_lb[o]);
                if (last) a_tq[o] = fmaf(osv[8 + k2], (float)qb[k2], a_tq[o]);
            }
        }
    }

    for (int o = 0; o < 8; ++o) {
        int b = o * 4 + grp;
        _Float16 v16 = (_Float16)a_tr[o];
        int p = hh & 63;
        rwP[t * 4096 + ((p >> 3) << 9) + ((2 * b + (hh >> 6)) << 3) + (p & 7)] = v16;
        int q = ((hh & 1) << 5) + b;
        clP[t * 4096 + ((q >> 3) << 9) + ((hh >> 1) << 3) + (q & 7)] = v16;
        lblT[t * 4096 + hh * 32 + b] = a_lb[o];
        if (last) outq[b * 128 + hh] = a_tq[o];
    }
}

// ---------------- step building blocks ----------------
#define DPP_ADD(S, CTRL)                                                           \
  do { int _d = __builtin_amdgcn_update_dpp(0, __float_as_int(S), (CTRL), 0xF,     \
                                            0xF, true);                            \
       (S) += __int_as_float(_d); } while (0)

#if __has_builtin(__builtin_amdgcn_fdot2)
#define FDOT2(ci, gi, acc)                                                         \
  __builtin_amdgcn_fdot2(__builtin_bit_cast(h2, (ci)),                             \
                         __builtin_bit_cast(h2, (gi)), (acc), false)
#else
static __device__ __forceinline__ float fdot2_sw(int a, int b, float c) {
    h2 ha = __builtin_bit_cast(h2, a), hb2 = __builtin_bit_cast(h2, b);
    return fmaf((float)ha.y, (float)hb2.y, fmaf((float)ha.x, (float)hb2.x, c));
}
#define FDOT2(ci, gi, acc) fdot2_sw((ci), (gi), (acc))
#endif

// ---------------- K3: Adam scan — 1 h per wave, lean fdot2 step (r12) ----------------
__global__
__attribute__((amdgpu_flat_work_group_size(64, 64), amdgpu_waves_per_eu(1, 1)))
void k_scan(
    const _Float16* __restrict__ rwP, const _Float16* __restrict__ clP,
    const float* __restrict__ lblT,
    const float* __restrict__ Wm0, const float* __restrict__ bm0,
    const float* __restrict__ outq, float* __restrict__ hi_ws) {
    const int h = blockIdx.x;
    const int lane = threadIdx.x;
    const int row = lane >> 1;
    const int hf = lane & 1;
    const int hf32i = hf * 32;           // int-pair base into w16
    const int lblidx = h * 32 + row;

    __shared__ __align__(16) int w16[64];      // fp16 w copy (pairs)
    __shared__ __align__(16) float ew[128];    // fp32 epilogue exchange

    // Adam state: lane owns Wm[h][2*lane], Wm[h][2*lane+1]
    float2 wv = *(const float2*)&Wm0[h * 128 + 2 * lane];
    float w0 = wv.x, w1 = wv.y;
    float mW0 = 0.f, vW0 = 0.f, mW1 = 0.f, vW1 = 0.f;
    float bm = bm0[h];
    float mb = 0.f, vb = 0.f, pb1 = 1.f, pb2 = 1.f;

    w16[lane] = __builtin_bit_cast(int, __builtin_amdgcn_cvt_pkrtz(w0, w1));

    h8 rw[8], cl[8];
    float lbl;
    {
        const h8* rs = (const h8*)(rwP);
        const h8* cs = (const h8*)(clP);
        #pragma unroll
        for (int j = 0; j < 8; ++j) rw[j] = rs[j * 64 + lane];
        #pragma unroll
        for (int j = 0; j < 8; ++j) cl[j] = cs[j * 64 + lane];
        lbl = lblT[lblidx];
    }

    const float cg = 2.0f / 4096.0f;
    const float lr = 0.01f, BB1 = 0.9f, BB2 = 0.999f;
    const float OB1 = 0.1f, OB2 = 0.001f;
    const float SEPS = 1e-16f;

    for (int t = 0; t < T_; ++t) {
        pb1 *= BB1; pb2 *= BB2;
        const float na = (-lr) * __builtin_amdgcn_sqrtf(1.0f - pb2) *
                         __builtin_amdgcn_rcpf(1.0f - pb1);
        const int tpre = (t + 1 < T_) ? (t + 1) : (T_ - 1);

        // ---- phase A: pred via fdot2 against fp16 w in LDS ----
        float g;
        {
            float f0 = 0.f, f1 = 0.f, f2 = 0.f, f3 = 0.f;
            #pragma unroll
            for (int j = 0; j < 8; ++j) {
                int4 xj = __builtin_bit_cast(int4, rw[j]);
                int4 wj = *(const int4*)&w16[hf32i + 4 * j];
                f0 = FDOT2(xj.x, wj.x, f0); f1 = FDOT2(xj.y, wj.y, f1);
                f2 = FDOT2(xj.z, wj.z, f2); f3 = FDOT2(xj.w, wj.w, f3);
            }
            float pp = (f0 + f2) + (f1 + f3);
            int po = __builtin_amdgcn_update_dpp(0, __float_as_int(pp), 0xB1, 0xF, 0xF, true);
            g = (pp + __int_as_float(po)) + bm - lbl;   // unscaled grad
        }

        // prefetch rows + lbl for t+1 (rw just consumed)
        {
            const h8* rs = (const h8*)(rwP + (size_t)tpre * 4096);
            #pragma unroll
            for (int j = 0; j < 8; ++j) rw[j] = rs[j * 64 + lane];
            lbl = lblT[(size_t)tpre * 4096 + lblidx];
        }

        // pack (g[2i], g[2i+1]) on lanes 4i
        int pkg;
        {
            int gnb = __builtin_amdgcn_update_dpp(0, __float_as_int(g), 0x4E, 0xF, 0xF, true);
            pkg = __builtin_bit_cast(int,
                __builtin_amdgcn_cvt_pkrtz(g, __int_as_float(gnb)));
        }
        // bias grad: exact fp32 butterfly over the 32 distinct g's
        float gsum = g;
        DPP_ADD(gsum, 0x4E); DPP_ADD(gsum, 0x124); DPP_ADD(gsum, 0x128);
        gsum += __shfl_xor(gsum, 16); gsum += __shfl_xor(gsum, 32);

        // 16 packed readlanes
        int gp[16];
        #pragma unroll
        for (int i = 0; i < 16; ++i)
            gp[i] = __builtin_amdgcn_readlane(pkg, 4 * i);

        // ---- phase B: 32 dot2 for this lane's two columns ----
        float gk0, gk1;
        {
            float f0 = 0.f, f1 = 0.f, f2 = 0.f, f3 = 0.f;
            float f4 = 0.f, f5 = 0.f, f6 = 0.f, f7 = 0.f;
            #pragma unroll
            for (int j = 0; j < 4; ++j) {
                int4 cj = __builtin_bit_cast(int4, cl[j]);
                f0 = FDOT2(cj.x, gp[4 * j + 0], f0); f1 = FDOT2(cj.y, gp[4 * j + 1], f1);
                f2 = FDOT2(cj.z, gp[4 * j + 2], f2); f3 = FDOT2(cj.w, gp[4 * j + 3], f3);
            }
            #pragma unroll
            for (int j = 0; j < 4; ++j) {
                int4 cj = __builtin_bit_cast(int4, cl[j + 4]);
                f4 = FDOT2(cj.x, gp[4 * j + 0], f4); f5 = FDOT2(cj.y, gp[4 * j + 1], f5);
                f6 = FDOT2(cj.z, gp[4 * j + 2], f6); f7 = FDOT2(cj.w, gp[4 * j + 3], f7);
            }
            gk0 = cg * ((f0 + f2) + (f1 + f3));
            gk1 = cg * ((f4 + f6) + (f5 + f7));
        }

        // prefetch cols for t+1 (cl just consumed)
        {
            const h8* cs = (const h8*)(clP + (size_t)tpre * 4096);
            #pragma unroll
            for (int j = 0; j < 8; ++j) cl[j] = cs[j * 64 + lane];
        }

        // ---- Adam W ----
        mW0 = fmaf(BB1, mW0, OB1 * gk0);
        vW0 = fmaf(BB2, vW0, OB2 * gk0 * gk0);
        w0 = fmaf(mW0 * __builtin_amdgcn_rsqf(vW0 + SEPS), na, w0);
        mW1 = fmaf(BB1, mW1, OB1 * gk1);
        vW1 = fmaf(BB2, vW1, OB2 * gk1 * gk1);
        w1 = fmaf(mW1 * __builtin_amdgcn_rsqf(vW1 + SEPS), na, w1);

        w16[lane] = __builtin_bit_cast(int, __builtin_amdgcn_cvt_pkrtz(w0, w1));

        // bias Adam (redundant on all lanes; off the w critical chain)
        {
            float gb = cg * gsum;
            mb = fmaf(BB1, mb, OB1 * gb);
            vb = fmaf(BB2, vb, OB2 * gb * gb);
            bm = fmaf(mb * __builtin_amdgcn_rsqf(vb + SEPS), na, bm);
        }
    }

    // ---- epilogue: hi[:,h] = outq @ Wm_final[h,:] + bm_final (fp32 exact) ----
    *(float2*)&ew[2 * lane] = make_float2(w0, w1);
    {
        const int rowbase = row * 128 + hf * 64;
        float a0 = 0.f, a1 = 0.f, a2 = 0.f, a3 = 0.f;
        #pragma unroll
        for (int j = 0; j < 16; ++j) {
            float4 xv = ((const float4*)(outq + rowbase))[j];
            float4 wv4 = *(const float4*)&ew[hf * 64 + 4 * j];
            a0 = fmaf(xv.x, wv4.x, a0); a1 = fmaf(xv.y, wv4.y, a1);
            a2 = fmaf(xv.z, wv4.z, a2); a3 = fmaf(xv.w, wv4.w, a3);
        }
        float pp = (a0 + a2) + (a1 + a3);
        int po = __builtin_amdgcn_update_dpp(0, __float_as_int(pp), 0xB1, 0xF, 0xF, true);
        float pred = pp + __int_as_float(po);
        if (hf == 0) hi_ws[row * 128 + h] = pred + bm;
    }
}

// ---------------- K4: y = hi@W_ho.T + b_o ; out = y@out_W.T + out_b ----------------
__global__ void k_out(const float* __restrict__ hi, const float* __restrict__ Who,
                      const float* __restrict__ bo, const float* __restrict__ outW,
                      const float* __restrict__ outb, float* __restrict__ dout) {
    int b = blockIdx.x, hh = threadIdx.x;
    __shared__ float hrow[128];
    __shared__ float part[2];
    hrow[hh] = hi[b * 128 + hh];
    __syncthreads();
    float acc = bo[hh];
    #pragma unroll 4
    for (int k = 0; k < 128; ++k) acc += hrow[k] * Who[hh * 128 + k];
    float v = acc * outW[hh];
    v += __shfl_down(v, 32, 64);
    v += __shfl_down(v, 16, 64);
    v += __shfl_down(v, 8, 64);
    v += __shfl_down(v, 4, 64);
    v += __shfl_down(v, 2, 64);
    v += __shfl_down(v, 1, 64);
    if ((hh & 63) == 0) part[hh >> 6] = v;
    __syncthreads();
    if (hh == 0) dout[b] = part[0] + part[1] + outb[0];
}

extern "C" void kernel_launch(void* const* d_in, const int* in_sizes, int n_in,
                              void* d_out, int out_size, void* d_ws, size_t ws_size,
                              hipStream_t stream) {
    (void)in_sizes; (void)n_in; (void)out_size; (void)ws_size;
    const float* in1   = (const float*)d_in[0];
    const float* in2   = (const float*)d_in[1];
    const float* in3   = (const float*)d_in[2];
    const float* h     = (const float*)d_in[3];
    const float* Wih   = (const float*)d_in[4];
    const float* Whh   = (const float*)d_in[5];
    const float* bh    = (const float*)d_in[6];
    const float* Who   = (const float*)d_in[7];
    const float* bo    = (const float*)d_in[8];
    const float* wl    = (const float*)d_in[9];
    const float* bl    = (const float*)d_in[10];
    const float* wsc   = (const float*)d_in[11];
    const float* bsc   = (const float*)d_in[12];
    const float* tk    = (const float*)d_in[13];
    const float* tv    = (const float*)d_in[14];
    const float* tq    = (const float*)d_in[15];
    const float* Wm0   = (const float*)d_in[16];
    const float* bm0   = (const float*)d_in[17];
    const float* outW  = (const float*)d_in[18];
    const float* outb  = (const float*)d_in[19];
    float* out = (float*)d_out;

    float* wsf = (float*)d_ws;
    float*    xf    = wsf;                               // 49152 f
    float*    hb    = wsf + 49152;                       // 4096 f
    _Float16* rwH   = (_Float16*)(wsf + 53248);          // 1048576 halfs
    _Float16* clH   = (_Float16*)(wsf + 53248 + 524288); // 1048576 halfs
    float*    lblT  = wsf + 53248 + 1048576;             // 1048576 f
    float*    outq  = wsf + 53248 + 2097152;             // 4096 f
    float*    hi_ws = wsf + 53248 + 2101248;             // 4096 f

    k_front<<<dim3(32, 7), 256, 0, stream>>>(in1, in2, wl, bl, wsc, bsc,
                                             h, Whh, bh, xf, hb, out);
    k_feat<<<256, 512, 0, stream>>>(xf, in3, hb, Wih, tk, tv, tq,
                                    rwH, clH, lblT, outq);
    k_scan<<<128, 64, 0, stream>>>(rwH, clH, lblT, Wm0, bm0, outq, hi_ws);
    k_out<<<32, 128, 0, stream>>>(hi_ws, Who, bo, outW, outb, out);
}

// Round 16
// 174.017 us; speedup vs baseline: 2.7290x; 1.1376x over previous
//
#include <hip/hip_runtime.h>
#include <math.h>

#define B_ 32
#define T_ 256
#define H_ 128
#define KL_ 500
#define KS_ 10

typedef _Float16 h8 __attribute__((ext_vector_type(8)));  // 16B = 8 fp16
typedef _Float16 h2 __attribute__((ext_vector_type(2)));

// ---------------- K1: convs (+ fused hb, + na table) ----------------
// grid (32, 8): oc 0..2 conv_l, 3..5 conv_s, 6 hb, 7 Adam bias-correction table
__global__ void k_front(const float* __restrict__ in1, const float* __restrict__ in2,
                        const float* __restrict__ wl, const float* __restrict__ bl,
                        const float* __restrict__ ws, const float* __restrict__ bs,
                        const float* __restrict__ h, const float* __restrict__ Whh,
                        const float* __restrict__ bh,
                        float* __restrict__ xf, float* __restrict__ hb,
                        float* __restrict__ naT, float* __restrict__ dout) {
    int b = blockIdx.x, oc = blockIdx.y;
    int t = threadIdx.x;  // 256 threads
    if (oc == 7) {        // na[t] = -lr*sqrt(1-b2^(t+1))/(1-b1^(t+1)), exact
        if (b == 0)
            naT[t] = -0.01f * sqrtf(1.0f - powf(0.999f, (float)(t + 1)))
                           / (1.0f - powf(0.9f, (float)(t + 1)));
        return;
    }
    if (oc == 6) {
        __shared__ float hrow[128];
        if (t < 128) hrow[t] = h[b * 128 + t];
        __syncthreads();
        if (t < 128) {
            float acc = bh[t];
            #pragma unroll 4
            for (int k = 0; k < 128; ++k) acc += hrow[k] * Whh[t * 128 + k];
            hb[b * 128 + t] = acc;
            dout[32 + b * 128 + t] = hrow[t];
        }
        return;
    }
    __shared__ float s_in[755 * 3];
    __shared__ float s_w[3 * KL_];
    if (oc < 3) {
        int o = oc;
        for (int i = t; i < 755 * 3; i += 256) s_in[i] = in1[b * 755 * 3 + i];
        for (int i = t; i < 3 * KL_; i += 256) s_w[i] = wl[o * 3 * KL_ + i];
        __syncthreads();
        float acc = bl[o];
        for (int i = 0; i < 3; ++i) {
            const float* wrow = &s_w[i * KL_];
            #pragma unroll 4
            for (int k = 0; k < KL_; ++k)
                acc += s_in[(t + k) * 3 + i] * wrow[k];
        }
        xf[(b * T_ + t) * 6 + o] = acc;
    } else {
        int o = oc - 3;
        for (int i = t; i < 265 * 3; i += 256) s_in[i] = in2[b * 265 * 3 + i];
        for (int i = t; i < 3 * KS_; i += 256) s_w[i] = ws[o * 3 * KS_ + i];
        __syncthreads();
        float acc = bs[o];
        for (int i = 0; i < 3; ++i) {
            #pragma unroll
            for (int k = 0; k < KS_; ++k)
                acc += s_in[(t + k) * 3 + i] * s_w[i * KS_ + k];
        }
        xf[(b * T_ + t) * 6 + 3 + o] = acc;
    }
}

// ---------------- K2: features -> lane-permuted fp16 tiles ----------------
// tq/outq handling moved to k_out (block 255 just exports out_s). LDS 86KB.
#define TSTR 136

__global__ void k_feat(const float* __restrict__ xf, const float* __restrict__ in3,
                       const float* __restrict__ hb, const float* __restrict__ Wih,
                       const float* __restrict__ tk, const float* __restrict__ tv,
                       _Float16* __restrict__ rwP, _Float16* __restrict__ clP,
                       float* __restrict__ lblT, float* __restrict__ o255) {
    int t = blockIdx.x;
    int tid = threadIdx.x;             // 0..511
    const int hh = tid & 127;
    const int grp = tid >> 7;          // 0..3

    __shared__ __align__(16) _Float16 tkT[128 * TSTR];
    __shared__ __align__(16) _Float16 tvT[128 * TSTR];
    __shared__ __align__(16) float out_s[B_ * H_];

    for (int j = 0; j < 8; ++j) {
        int idx = j * 512 + tid;
        int b = idx >> 7, hx = idx & 127;
        const float* w = &Wih[hx * 9];
        const float* x6 = &xf[(b * T_ + t) * 6];
        const float* x3 = &in3[(b * T_ + t) * 3];
        float acc = hb[idx];
        acc += x6[0] * w[0] + x6[1] * w[1] + x6[2] * w[2]
             + x6[3] * w[3] + x6[4] * w[4] + x6[5] * w[5]
             + x3[0] * w[6] + x3[1] * w[7] + x3[2] * w[8];
        out_s[idx] = acc;
    }
    for (int i = tid; i < 16384; i += 512) {
        int k = i >> 7, hx = i & 127;
        tkT[hx * TSTR + k] = (_Float16)tk[i];
        tvT[hx * TSTR + k] = (_Float16)tv[i];
    }
    __syncthreads();

    if (t == T_ - 1) {  // export out_255 (fp32) for k_out's tq/epilogue path
        for (int j = 0; j < 8; ++j) o255[j * 512 + tid] = out_s[j * 512 + tid];
    }

    float a_tr[8], a_lb[8];
    #pragma unroll
    for (int o = 0; o < 8; ++o) { a_tr[o] = 0.f; a_lb[o] = 0.f; }

    for (int kc = 0; kc < 8; ++kc) {
        const int4* tk4 = (const int4*)&tkT[hh * TSTR + kc * 16];
        const int4* tv4 = (const int4*)&tvT[hh * TSTR + kc * 16];
        h8 ka = __builtin_bit_cast(h8, tk4[0]), kb = __builtin_bit_cast(h8, tk4[1]);
        h8 va = __builtin_bit_cast(h8, tv4[0]), vb = __builtin_bit_cast(h8, tv4[1]);
        #pragma unroll
        for (int o = 0; o < 8; ++o) {
            int b = o * 4 + grp;
            const float4* os4 = (const float4*)&out_s[b * 128 + kc * 16];
            float4 q0 = os4[0], q1 = os4[1], q2 = os4[2], q3 = os4[3];
            float osv[16] = {q0.x, q0.y, q0.z, q0.w, q1.x, q1.y, q1.z, q1.w,
                             q2.x, q2.y, q2.z, q2.w, q3.x, q3.y, q3.z, q3.w};
            #pragma unroll
            for (int k2 = 0; k2 < 8; ++k2) {
                a_tr[o] = fmaf(osv[k2], (float)ka[k2], a_tr[o]);
                a_lb[o] = fmaf(osv[k2], (float)va[k2], a_lb[o]);
            }
            #pragma unroll
            for (int k2 = 0; k2 < 8; ++k2) {
                a_tr[o] = fmaf(osv[8 + k2], (float)kb[k2], a_tr[o]);
                a_lb[o] = fmaf(osv[8 + k2], (float)vb[k2], a_lb[o]);
            }
        }
    }

    for (int o = 0; o < 8; ++o) {
        int b = o * 4 + grp;
        _Float16 v16 = (_Float16)a_tr[o];
        int p = hh & 63;
        rwP[t * 4096 + ((p >> 3) << 9) + ((2 * b + (hh >> 6)) << 3) + (p & 7)] = v16;
        int q = ((hh & 1) << 5) + b;
        clP[t * 4096 + ((q >> 3) << 9) + ((hh >> 1) << 3) + (q & 7)] = v16;
        lblT[t * 4096 + hh * 32 + b] = a_lb[o];
    }
}

// ---------------- step building blocks ----------------
#define DPP_ADD(S, CTRL)                                                           \
  do { int _d = __builtin_amdgcn_update_dpp(0, __float_as_int(S), (CTRL), 0xF,     \
                                            0xF, true);                            \
       (S) += __int_as_float(_d); } while (0)

#if __has_builtin(__builtin_amdgcn_fdot2)
#define FDOT2(ci, gi, acc)                                                         \
  __builtin_amdgcn_fdot2(__builtin_bit_cast(h2, (ci)),                             \
                         __builtin_bit_cast(h2, (gi)), (acc), false)
#else
static __device__ __forceinline__ float fdot2_sw(int a, int b, float c) {
    h2 ha = __builtin_bit_cast(h2, a), hb2 = __builtin_bit_cast(h2, b);
    return fmaf((float)ha.y, (float)hb2.y, fmaf((float)ha.x, (float)hb2.x, c));
}
#define FDOT2(ci, gi, acc) fdot2_sw((ci), (gi), (acc))
#endif

// ---------------- K3: Adam scan — 1 h/wave, table-na, folded-cg, x2 unroll ----------------
// Adam constants folded with cg: m' = cg*m, v' = cg^2*v -> update identical with
// OB1c=0.1*cg, OB2c=0.001*cg^2, eps' = 1e-16*cg^2.
#define SCAN_STEP(TT)                                                              \
  do {                                                                             \
    const int tpre = ((TT) + 1 < T_) ? ((TT) + 1) : (T_ - 1);                      \
    /* phase A: pred via fdot2 against fp16 w in LDS */                            \
    float g;                                                                       \
    {                                                                              \
      float f0 = 0.f, f1 = 0.f, f2 = 0.f, f3 = 0.f;                                \
      _Pragma("unroll")                                                            \
      for (int j = 0; j < 8; ++j) {                                                \
        int4 xj = __builtin_bit_cast(int4, rw[j]);                                 \
        int4 wj = *(const int4*)&w16[hf32i + 4 * j];                               \
        f0 = FDOT2(xj.x, wj.x, f0); f1 = FDOT2(xj.y, wj.y, f1);                    \
        f2 = FDOT2(xj.z, wj.z, f2); f3 = FDOT2(xj.w, wj.w, f3);                    \
      }                                                                            \
      float pp = (f0 + f2) + (f1 + f3);                                            \
      int po = __builtin_amdgcn_update_dpp(0, __float_as_int(pp), 0xB1, 0xF, 0xF,  \
                                           true);                                  \
      g = (pp + __int_as_float(po)) + bml;  /* unscaled grad */                    \
    }                                                                              \
    /* prefetch rows + lbl + na for tpre */                                        \
    float lbln, nan_;                                                              \
    {                                                                              \
      const h8* rs = (const h8*)(rwP + (size_t)tpre * 4096);                       \
      _Pragma("unroll")                                                            \
      for (int j = 0; j < 8; ++j) rw[j] = rs[j * 64 + lane];                       \
      lbln = lblT[(size_t)tpre * 4096 + lblidx];                                   \
      nan_ = naT[tpre];                                                            \
    }                                                                              \
    /* pack (g[2i], g[2i+1]) on lanes 4i */                                        \
    int pkg;                                                                       \
    {                                                                              \
      int gnb = __builtin_amdgcn_update_dpp(0, __float_as_int(g), 0x4E, 0xF, 0xF,  \
                                            true);                                 \
      pkg = __builtin_bit_cast(int,                                                \
          __builtin_amdgcn_cvt_pkrtz(g, __int_as_float(gnb)));                     \
    }                                                                              \
    /* bias grad: exact fp32 butterfly over the 32 distinct g's */                 \
    float gsum = g;                                                                \
    DPP_ADD(gsum, 0x4E); DPP_ADD(gsum, 0x124); DPP_ADD(gsum, 0x128);               \
    gsum += __shfl_xor(gsum, 16); gsum += __shfl_xor(gsum, 32);                    \
    /* 16 packed readlanes */                                                      \
    int gp[16];                                                                    \
    _Pragma("unroll")                                                              \
    for (int i = 0; i < 16; ++i)                                                   \
      gp[i] = __builtin_amdgcn_readlane(pkg, 4 * i);                               \
    /* phase B: 32 dot2 for this lane's two columns (raw dots) */                  \
    float d0, d1;                                                                  \
    {                                                                              \
      float f0 = 0.f, f1 = 0.f, f2 = 0.f, f3 = 0.f;                                \
      float f4 = 0.f, f5 = 0.f, f6 = 0.f, f7 = 0.f;                                \
      _Pragma("unroll")                                                            \
      for (int j = 0; j < 4; ++j) {                                                \
        int4 cj = __builtin_bit_cast(int4, cl[j]);                                 \
        f0 = FDOT2(cj.x, gp[4 * j + 0], f0); f1 = FDOT2(cj.y, gp[4 * j + 1], f1);  \
        f2 = FDOT2(cj.z, gp[4 * j + 2], f2); f3 = FDOT2(cj.w, gp[4 * j + 3], f3);  \
      }                                                                            \
      _Pragma("unroll")                                                            \
      for (int j = 0; j < 4; ++j) {                                                \
        int4 cj = __builtin_bit_cast(int4, cl[j + 4]);                             \
        f4 = FDOT2(cj.x, gp[4 * j + 0], f4); f5 = FDOT2(cj.y, gp[4 * j + 1], f5);  \
        f6 = FDOT2(cj.z, gp[4 * j + 2], f6); f7 = FDOT2(cj.w, gp[4 * j + 3], f7);  \
      }                                                                            \
      d0 = (f0 + f2) + (f1 + f3);                                                  \
      d1 = (f4 + f6) + (f5 + f7);                                                  \
    }                                                                              \
    /* prefetch cols for tpre */                                                   \
    {                                                                              \
      const h8* cs = (const h8*)(clP + (size_t)tpre * 4096);                       \
      _Pragma("unroll")                                                            \
      for (int j = 0; j < 8; ++j) cl[j] = cs[j * 64 + lane];                       \
    }                                                                              \
    /* Adam W (cg folded into constants) */                                        \
    mW0 = fmaf(BB1, mW0, OB1c * d0);                                               \
    vW0 = fmaf(BB2, vW0, OB2c * d0 * d0);                                          \
    w0 = fmaf(mW0 * __builtin_amdgcn_rsqf(vW0 + SEPSW), nav, w0);                  \
    mW1 = fmaf(BB1, mW1, OB1c * d1);                                               \
    vW1 = fmaf(BB2, vW1, OB2c * d1 * d1);                                          \
    w1 = fmaf(mW1 * __builtin_amdgcn_rsqf(vW1 + SEPSW), nav, w1);                  \
    w16[lane] = __builtin_bit_cast(int, __builtin_amdgcn_cvt_pkrtz(w0, w1));       \
    /* bias Adam (redundant on all lanes; off the w critical chain) */             \
    mb = fmaf(BB1, mb, OB1c * gsum);                                               \
    vb = fmaf(BB2, vb, OB2c * gsum * gsum);                                        \
    bm = fmaf(mb * __builtin_amdgcn_rsqf(vb + SEPSW), nav, bm);                    \
    bml = bm - lbln;                                                               \
    nav = nan_;                                                                    \
  } while (0)

__global__
__attribute__((amdgpu_flat_work_group_size(64, 64), amdgpu_waves_per_eu(1, 1)))
void k_scan(
    const _Float16* __restrict__ rwP, const _Float16* __restrict__ clP,
    const float* __restrict__ lblT, const float* __restrict__ naT,
    const float* __restrict__ Wm0, const float* __restrict__ bm0,
    float* __restrict__ wfinT, float* __restrict__ bmfin) {
    const int h = blockIdx.x;
    const int lane = threadIdx.x;
    const int hf32i = (lane & 1) * 32;   // int-pair base into w16
    const int lblidx = h * 32 + (lane >> 1);

    __shared__ __align__(16) int w16[64];      // fp16 w copy (pairs)

    float2 wv = *(const float2*)&Wm0[h * 128 + 2 * lane];
    float w0 = wv.x, w1 = wv.y;
    float mW0 = 0.f, vW0 = 0.f, mW1 = 0.f, vW1 = 0.f;
    float bm = bm0[h];
    float mb = 0.f, vb = 0.f;

    w16[lane] = __builtin_bit_cast(int, __builtin_amdgcn_cvt_pkrtz(w0, w1));

    h8 rw[8], cl[8];
    float bml, nav;
    {
        const h8* rs = (const h8*)(rwP);
        const h8* cs = (const h8*)(clP);
        #pragma unroll
        for (int j = 0; j < 8; ++j) rw[j] = rs[j * 64 + lane];
        #pragma unroll
        for (int j = 0; j < 8; ++j) cl[j] = cs[j * 64 + lane];
        bml = bm - lblT[lblidx];
        nav = naT[0];
    }

    const float cg = 2.0f / 4096.0f;
    const float BB1 = 0.9f, BB2 = 0.999f;
    const float OB1c = 0.1f * cg;              // 0.1 * cg
    const float OB2c = 0.001f * cg * cg;       // 0.001 * cg^2
    const float SEPSW = 1e-16f * cg * cg;      // eps scaled to folded v

    for (int t = 0; t < T_; t += 2) {
        SCAN_STEP(t);
        SCAN_STEP(t + 1);
    }

    // final weights out (transposed for coalesced consumption in k_out)
    wfinT[(2 * lane) * 128 + h] = w0;
    wfinT[(2 * lane + 1) * 128 + h] = w1;
    if (lane == 0) bmfin[h] = bm;
}

// ---------------- K4: outq -> hi -> y -> out (all fp32 exact) ----------------
__global__ void k_out(const float* __restrict__ o255, const float* __restrict__ tq,
                      const float* __restrict__ wfinT, const float* __restrict__ bmfin,
                      const float* __restrict__ Who, const float* __restrict__ bo,
                      const float* __restrict__ outW, const float* __restrict__ outb,
                      float* __restrict__ dout) {
    int b = blockIdx.x, hh = threadIdx.x;  // 32 blocks x 128 threads
    __shared__ float o255s[128], oqs[128], his[128];
    __shared__ float part[2];

    o255s[hh] = o255[b * 128 + hh];
    __syncthreads();
    float oq = 0.f;
    #pragma unroll 4
    for (int k = 0; k < 128; ++k) oq = fmaf(o255s[k], tq[k * 128 + hh], oq);
    oqs[hh] = oq;
    __syncthreads();
    float hi = bmfin[hh];
    #pragma unroll 4
    for (int k = 0; k < 128; ++k) hi = fmaf(oqs[k], wfinT[k * 128 + hh], hi);
    his[hh] = hi;
    __syncthreads();
    float acc = bo[hh];
    #pragma unroll 4
    for (int k = 0; k < 128; ++k) acc = fmaf(his[k], Who[hh * 128 + k], acc);
    float v = acc * outW[hh];
    v += __shfl_down(v, 32, 64);
    v += __shfl_down(v, 16, 64);
    v += __shfl_down(v, 8, 64);
    v += __shfl_down(v, 4, 64);
    v += __shfl_down(v, 2, 64);
    v += __shfl_down(v, 1, 64);
    if ((hh & 63) == 0) part[hh >> 6] = v;
    __syncthreads();
    if (hh == 0) dout[b] = part[0] + part[1] + outb[0];
}

extern "C" void kernel_launch(void* const* d_in, const int* in_sizes, int n_in,
                              void* d_out, int out_size, void* d_ws, size_t ws_size,
                              hipStream_t stream) {
    (void)in_sizes; (void)n_in; (void)out_size; (void)ws_size;
    const float* in1   = (const float*)d_in[0];
    const float* in2   = (const float*)d_in[1];
    const float* in3   = (const float*)d_in[2];
    const float* h     = (const float*)d_in[3];
    const float* Wih   = (const float*)d_in[4];
    const float* Whh   = (const float*)d_in[5];
    const float* bh    = (const float*)d_in[6];
    const float* Who   = (const float*)d_in[7];
    const float* bo    = (const float*)d_in[8];
    const float* wl    = (const float*)d_in[9];
    const float* bl    = (const float*)d_in[10];
    const float* wsc   = (const float*)d_in[11];
    const float* bsc   = (const float*)d_in[12];
    const float* tk    = (const float*)d_in[13];
    const float* tv    = (const float*)d_in[14];
    const float* tq    = (const float*)d_in[15];
    const float* Wm0   = (const float*)d_in[16];
    const float* bm0   = (const float*)d_in[17];
    const float* outW  = (const float*)d_in[18];
    const float* outb  = (const float*)d_in[19];
    float* out = (float*)d_out;

    float* wsf = (float*)d_ws;
    float*    xf    = wsf;                                   // 49152 f
    float*    hb    = wsf + 49152;                           // 4096 f
    _Float16* rwH   = (_Float16*)(wsf + 53248);              // 1048576 halfs
    _Float16* clH   = (_Float16*)(wsf + 53248 + 524288);     // 1048576 halfs
    float*    lblT  = wsf + 53248 + 1048576;                 // 1048576 f
    float*    naT   = wsf + 53248 + 2097152;                 // 256 f
    float*    o255  = wsf + 53248 + 2097408;                 // 4096 f
    float*    wfinT = wsf + 53248 + 2101504;                 // 16384 f
    float*    bmfin = wsf + 53248 + 2117888;                 // 128 f

    k_front<<<dim3(32, 8), 256, 0, stream>>>(in1, in2, wl, bl, wsc, bsc,
                                             h, Whh, bh, xf, hb, naT, out);
    k_feat<<<256, 512, 0, stream>>>(xf, in3, hb, Wih, tk, tv,
                                    rwH, clH, lblT, o255);
    k_scan<<<128, 64, 0, stream>>>(rwH, clH, lblT, naT, Wm0, bm0, wfinT, bmfin);
    k_out<<<32, 128, 0, stream>>>(o255, tq, wfinT, bmfin, Who, bo, outW, outb, out);
}